// Round 1
// baseline (1059.793 us; speedup 1.0000x reference)
//
#include <hip/hip_runtime.h>

#define M_ 16
#define H_ 32
#define D_ 128
#define P_ 8192
#define N_ 4096
#define PM_ 8208   // P + M
#define NG_ 2052   // PM/4 groups of 4 p's

// workspace layout (float offsets)
#define WS_Q    0          // [32][16][128]
#define WS_K    65536      // [32][16][128]
#define WS_V    131072     // [32][16][128]
#define WS_OUN  196608     // [32][16][128] unnormalized O
#define WS_S1   262144     // [512]
#define WS_S2   262656     // [512]
#define WS_IS2  263168     // [512]
#define WS_XQ   263680     // x_norm as float4 [1024][16] (quad-of-n major, m minor)
#define WS_E2   329216     // [32][16][8208]
// total = 4,531,712 floats = 18.1 MB

// ---------------- Kernel A: RMS norm, write transposed-quad layout ----------------
__global__ __launch_bounds__(256) void rmsnorm_kernel(const float* __restrict__ X,
                                                      float* __restrict__ ws) {
  int m = blockIdx.x, t = threadIdx.x;
  __shared__ float red[256];
  const float4* X4 = (const float4*)(X + (size_t)m * N_);
  float s = 0.f;
  #pragma unroll
  for (int q = 0; q < 4; q++) {
    float4 v = X4[t + q * 256];
    s += v.x * v.x + v.y * v.y + v.z * v.z + v.w * v.w;
  }
  red[t] = s;
  __syncthreads();
  for (int off = 128; off > 0; off >>= 1) {
    if (t < off) red[t] += red[t + off];
    __syncthreads();
  }
  float scale = rsqrtf(red[0] * (1.0f / N_));
  float4* xq = (float4*)(ws + WS_XQ);
  #pragma unroll
  for (int q = 0; q < 4; q++) {
    int nq = t + q * 256;
    float4 v = X4[nq];
    v.x *= scale; v.y *= scale; v.z *= scale; v.w *= scale;
    xq[nq * 16 + m] = v;  // xq[n/4][m]
  }
}

// ---------------- Kernel B: QKV projection ----------------
// 12288 output columns (q|k|v). lane <-> column j within a 64-wide tile.
// W tile staged via per-wave LDS with XOR swizzle; x broadcast from L1.
// K-split x16 over n, partials combined with hardware f32 atomics.
__global__ __launch_bounds__(256, 4) void proj_kernel(const float* __restrict__ Wq,
                                                      const float* __restrict__ Wk,
                                                      const float* __restrict__ Wv,
                                                      float* __restrict__ ws) {
  __shared__ float tile[4 * 64 * 32];  // 32 KB, one 8KB tile per wave
  int widx = threadIdx.x >> 6, lane = threadIdx.x & 63;
  int w = blockIdx.x * 4 + widx;   // 0..3071
  int kc = w / 192;                // k-chunk 0..15 (uniform within a block)
  int jt = w % 192;                // j-tile 0..191
  int jj0 = jt * 64;
  int sel = jj0 >> 12;             // 0=q 1=k 2=v
  int j0 = jj0 & 4095;
  const float* Wm = (sel == 0) ? Wq : ((sel == 1) ? Wk : Wv);
  float* outp = ws + ((sel == 0) ? WS_Q : ((sel == 1) ? WS_K : WS_V));
  const float4* xq = (const float4*)(ws + WS_XQ);
  float* tl = tile + widx * 2048;

  float acc[16];
  #pragma unroll
  for (int m = 0; m < 16; m++) acc[m] = 0.f;

  int n0 = kc * 256;
  int r_ = lane >> 3, c_ = lane & 7;
  for (int ti = 0; ti < 8; ti++) {
    int nb = n0 + ti * 32;
    // stage 64 rows x 32 floats, XOR-swizzled chunks
    #pragma unroll
    for (int i = 0; i < 8; i++) {
      int r = i * 8 + r_;
      float4 g = *(const float4*)(Wm + (size_t)(j0 + r) * N_ + nb + c_ * 4);
      *(float4*)&tl[r * 32 + ((c_ ^ (r & 7)) << 2)] = g;
    }
    // 8 n-steps of 4
    #pragma unroll
    for (int k = 0; k < 8; k++) {
      float4 w4 = *(const float4*)&tl[lane * 32 + ((k ^ (lane & 7)) << 2)];
      int qbase = ((nb >> 2) + k) * 16;
      #pragma unroll
      for (int m = 0; m < 16; m++) {
        float4 xm = xq[qbase + m];  // wave-uniform -> broadcast
        acc[m] += xm.x * w4.x + xm.y * w4.y + xm.z * w4.z + xm.w * w4.w;
      }
    }
  }
  int j = j0 + lane;
  int h = j >> 7, d = j & 127;
  #pragma unroll
  for (int m = 0; m < 16; m++)
    unsafeAtomicAdd(&outp[(h * 16 + m) * 128 + d], acc[m]);
}

// ---------------- Kernel C1: attention main pass ----------------
// lane = (m = lane&15, dq = lane>>4). Q in 32 VGPRs, O accumulated in 32 VGPRs.
// Per 4-p group: QK^T partial dots -> shfl-xor reduce over dq -> exp ->
// e2 store + s1/s2 accumulate -> PV accumulate. No LDS.
__global__ __launch_bounds__(256, 4) void attn_kernel(const float* __restrict__ cacheK,
                                                      const float* __restrict__ cacheV,
                                                      const float* __restrict__ noise,
                                                      const float* __restrict__ taup,
                                                      float* __restrict__ ws) {
  int h = blockIdx.x >> 5, b = blockIdx.x & 31;
  int widx = threadIdx.x >> 6, lane = threadIdx.x & 63;
  int m = lane & 15, dq = lane >> 4;
  int w64 = b * 4 + widx;  // 0..127 within head
  float inv_tau = 1.0f / taup[0];

  const float* qp = ws + WS_Q + (size_t)(h * 16 + m) * 128 + dq * 32;
  float qv[32];
  #pragma unroll
  for (int i = 0; i < 8; i++) {
    float4 t = *(const float4*)(qp + i * 4);
    qv[i * 4] = t.x; qv[i * 4 + 1] = t.y; qv[i * 4 + 2] = t.z; qv[i * 4 + 3] = t.w;
  }
  float oacc[32];
  #pragma unroll
  for (int i = 0; i < 32; i++) oacc[i] = 0.f;
  float s1 = 0.f, s2 = 0.f;

  const float* nrow = noise + (size_t)(h * 16 + m) * PM_;
  float* e2row = ws + WS_E2 + (size_t)(h * 16 + m) * PM_;
  const float* kc_base = cacheK + (size_t)h * P_ * D_;
  const float* vc_base = cacheV + (size_t)h * P_ * D_;
  const float* kn_base = ws + WS_K + (size_t)h * 16 * 128;
  const float* vn_base = ws + WS_V + (size_t)h * 16 * 128;

  for (int g = w64; g < NG_; g += 128) {
    int p0 = g * 4;
    const float *kb, *vb;
    if (p0 < P_) { kb = kc_base + (size_t)p0 * D_; vb = vc_base + (size_t)p0 * D_; }
    else { kb = kn_base + (size_t)(p0 - P_) * D_; vb = vn_base + (size_t)(p0 - P_) * D_; }

    float cc[4];
    #pragma unroll
    for (int pp = 0; pp < 4; pp++) {
      const float4* kr = (const float4*)(kb + pp * D_ + dq * 32);
      float a0 = 0.f, a1 = 0.f;
      #pragma unroll
      for (int i = 0; i < 8; i += 2) {
        float4 k4 = kr[i];
        a0 += qv[i * 4] * k4.x;     a0 += qv[i * 4 + 1] * k4.y;
        a0 += qv[i * 4 + 2] * k4.z; a0 += qv[i * 4 + 3] * k4.w;
        float4 k5 = kr[i + 1];
        a1 += qv[i * 4 + 4] * k5.x; a1 += qv[i * 4 + 5] * k5.y;
        a1 += qv[i * 4 + 6] * k5.z; a1 += qv[i * 4 + 7] * k5.w;
      }
      cc[pp] = a0 + a1;
    }
    #pragma unroll
    for (int pp = 0; pp < 4; pp++) {
      cc[pp] += __shfl_xor(cc[pp], 16, 64);
      cc[pp] += __shfl_xor(cc[pp], 32, 64);
    }
    float4 nz = *(const float4*)(nrow + p0);
    float e1v[4], e2v[4];
    e1v[0] = __expf(cc[0]); e1v[1] = __expf(cc[1]);
    e1v[2] = __expf(cc[2]); e1v[3] = __expf(cc[3]);
    e2v[0] = __expf((cc[0] + nz.x) * inv_tau);
    e2v[1] = __expf((cc[1] + nz.y) * inv_tau);
    e2v[2] = __expf((cc[2] + nz.z) * inv_tau);
    e2v[3] = __expf((cc[3] + nz.w) * inv_tau);
    s1 += e1v[0] + e1v[1] + e1v[2] + e1v[3];
    s2 += e2v[0] + e2v[1] + e2v[2] + e2v[3];
    if (dq == 0)
      *(float4*)(e2row + p0) = make_float4(e2v[0], e2v[1], e2v[2], e2v[3]);

    #pragma unroll
    for (int pp = 0; pp < 4; pp++) {
      const float4* vr = (const float4*)(vb + pp * D_ + dq * 32);
      float e = e1v[pp];
      #pragma unroll
      for (int i = 0; i < 8; i++) {
        float4 v4 = vr[i];
        oacc[i * 4] += e * v4.x;     oacc[i * 4 + 1] += e * v4.y;
        oacc[i * 4 + 2] += e * v4.z; oacc[i * 4 + 3] += e * v4.w;
      }
    }
  }

  if (dq == 0) {
    unsafeAtomicAdd(ws + WS_S1 + h * 16 + m, s1);
    unsafeAtomicAdd(ws + WS_S2 + h * 16 + m, s2);
  }
  float* ob = ws + WS_OUN + (size_t)(h * 16 + m) * 128 + dq * 32;
  #pragma unroll
  for (int i = 0; i < 32; i++) unsafeAtomicAdd(&ob[i], oacc[i]);
}

// ---------------- Kernel D: o2 epilogue + inverse s2 ----------------
__global__ __launch_bounds__(256) void epilogue_kernel(float* __restrict__ ws,
                                                       float* __restrict__ out) {
  int tid = blockIdx.x * 256 + threadIdx.x;
  if (tid < 512) ws[WS_IS2 + tid] = 1.0f / ws[WS_S2 + tid];
  // o2[m][h*128+d] = o_un[h][m][d] / s1[h][m]
  int mm = tid >> 12, j = tid & 4095;
  int h = j >> 7, d = j & 127;
  float s = ws[WS_S1 + h * 16 + mm];
  out[tid] = ws[WS_OUN + (size_t)(h * 16 + mm) * 128 + d] / s;
}

// ---------------- Kernel C2: c_out ----------------
__global__ __launch_bounds__(256) void cout_kernel(const float* __restrict__ ws,
                                                   float* __restrict__ out) {
  int tid = blockIdx.x * 256 + threadIdx.x;
  if (tid >= H_ * PM_) return;
  int h = tid / PM_, p = tid % PM_;
  const float* e2b = ws + WS_E2 + (size_t)h * 16 * PM_ + p;
  const float* is2 = ws + WS_IS2 + h * 16;
  float acc = 0.f;
  #pragma unroll
  for (int mm = 0; mm < 16; mm++) acc += e2b[(size_t)mm * PM_] * is2[mm];
  out[65536 + tid] = acc;
}

extern "C" void kernel_launch(void* const* d_in, const int* in_sizes, int n_in,
                              void* d_out, int out_size, void* d_ws, size_t ws_size,
                              hipStream_t stream) {
  const float* X     = (const float*)d_in[0];
  const float* Wq    = (const float*)d_in[1];
  const float* Wk    = (const float*)d_in[2];
  const float* Wv    = (const float*)d_in[3];
  const float* cK    = (const float*)d_in[4];
  const float* cV    = (const float*)d_in[5];
  const float* tau   = (const float*)d_in[6];
  const float* noise = (const float*)d_in[7];
  float* out = (float*)d_out;
  float* ws  = (float*)d_ws;

  // zero the atomic-accumulated regions (q/k/v, o_un, s1, s2) every call
  hipMemsetAsync(ws, 0, (size_t)263168 * sizeof(float), stream);

  rmsnorm_kernel<<<16, 256, 0, stream>>>(X, ws);
  proj_kernel<<<768, 256, 0, stream>>>(Wq, Wk, Wv, ws);
  attn_kernel<<<1024, 256, 0, stream>>>(cK, cV, noise, tau, ws);
  epilogue_kernel<<<256, 256, 0, stream>>>(ws, out);
  cout_kernel<<<1026, 256, 0, stream>>>(ws, out);
}

// Round 2
// 705.821 us; speedup vs baseline: 1.5015x; 1.5015x over previous
//
#include <hip/hip_runtime.h>

#define M_ 16
#define H_ 32
#define D_ 128
#define P_ 8192
#define N_ 4096
#define PM_ 8208   // P + M
#define NG_ 2052   // PM/4 groups of 4 p's

// workspace layout (float offsets) — no region needs pre-zeroing
#define WS_Q    0          // [32][16][128] q
#define WS_K    65536      // [32][16][128] new k
#define WS_V    131072     // [32][16][128] new v
#define WS_S1   196608     // [512] final denominators (exp(c))
#define WS_S2   197120     // [512] final denominators (perturbed)
#define WS_IS2  197632     // [512] 1/s2
#define WS_XQ   198144     // x_norm as float4 [1024][16] (n-quad major, m minor)
#define WS_E2   263680     // [32][16][8208] unnormalized perturbed exp
#define WS_PP   263680     // proj partials [16][16][12288] — ALIASES E2 (consumed before attn)
#define WS_PO   4466176    // attn O partials [32][32][16][128] (h, block, m, d)
#define WS_SP1  6563328    // [32*32*16] s1 partials per (h, block, m)
#define WS_SP2  6579712    // [32*32*16]
// total = 6,596,096 floats = 26.4 MB

// ---------------- Kernel A: RMS norm, write transposed-quad layout ----------------
__global__ __launch_bounds__(256) void rmsnorm_kernel(const float* __restrict__ X,
                                                      float* __restrict__ ws) {
  int m = blockIdx.x, t = threadIdx.x;
  __shared__ float red[256];
  const float4* X4 = (const float4*)(X + (size_t)m * N_);
  float s = 0.f;
  #pragma unroll
  for (int q = 0; q < 4; q++) {
    float4 v = X4[t + q * 256];
    s += v.x * v.x + v.y * v.y + v.z * v.z + v.w * v.w;
  }
  red[t] = s;
  __syncthreads();
  for (int off = 128; off > 0; off >>= 1) {
    if (t < off) red[t] += red[t + off];
    __syncthreads();
  }
  float scale = rsqrtf(red[0] * (1.0f / N_));
  float4* xq = (float4*)(ws + WS_XQ);
  #pragma unroll
  for (int q = 0; q < 4; q++) {
    int nq = t + q * 256;
    float4 v = X4[nq];
    v.x *= scale; v.y *= scale; v.z *= scale; v.w *= scale;
    xq[nq * 16 + m] = v;  // xq[n/4][m]
  }
}

// ---------------- Kernel B: QKV projection (k-split x16, partials to ws) ----------------
__global__ __launch_bounds__(256, 4) void proj_kernel(const float* __restrict__ Wq,
                                                      const float* __restrict__ Wk,
                                                      const float* __restrict__ Wv,
                                                      float* __restrict__ ws) {
  __shared__ float tile[4 * 64 * 32];  // 32 KB, one 8KB tile per wave
  int widx = threadIdx.x >> 6, lane = threadIdx.x & 63;
  int w = blockIdx.x * 4 + widx;   // 0..3071
  int kc = w / 192;                // k-chunk 0..15 (uniform within a block)
  int jt = w % 192;                // j-tile 0..191 over 12288 combined cols
  int jj0 = jt * 64;
  int sel = jj0 >> 12;             // 0=q 1=k 2=v
  int j0 = jj0 & 4095;
  const float* Wm = (sel == 0) ? Wq : ((sel == 1) ? Wk : Wv);
  const float4* xq = (const float4*)(ws + WS_XQ);
  float* tl = tile + widx * 2048;

  float acc[16];
  #pragma unroll
  for (int m = 0; m < 16; m++) acc[m] = 0.f;

  int n0 = kc * 256;
  int r_ = lane >> 3, c_ = lane & 7;
  for (int ti = 0; ti < 8; ti++) {
    int nb = n0 + ti * 32;
    #pragma unroll
    for (int i = 0; i < 8; i++) {
      int r = i * 8 + r_;
      float4 g = *(const float4*)(Wm + (size_t)(j0 + r) * N_ + nb + c_ * 4);
      *(float4*)&tl[r * 32 + ((c_ ^ (r & 7)) << 2)] = g;
    }
    #pragma unroll
    for (int k = 0; k < 8; k++) {
      float4 w4 = *(const float4*)&tl[lane * 32 + ((k ^ (lane & 7)) << 2)];
      int qbase = ((nb >> 2) + k) * 16;
      #pragma unroll
      for (int m = 0; m < 16; m++) {
        float4 xm = xq[qbase + m];  // wave-uniform -> broadcast
        acc[m] += xm.x * w4.x + xm.y * w4.y + xm.z * w4.z + xm.w * w4.w;
      }
    }
  }
  // partial store: PP[kc][m][jj0+lane], coalesced 256B per m
  float* pp = ws + WS_PP + (size_t)kc * 16 * 12288 + jj0 + lane;
  #pragma unroll
  for (int m = 0; m < 16; m++) pp[(size_t)m * 12288] = acc[m];
}

// ---------------- Kernel B2: reduce proj partials over kc ----------------
__global__ __launch_bounds__(256) void proj_reduce_kernel(float* __restrict__ ws) {
  int tid = blockIdx.x * 256 + threadIdx.x;  // 0..196607
  int m = tid / 12288;
  int j = tid - m * 12288;
  float acc = 0.f;
  #pragma unroll
  for (int kc = 0; kc < 16; kc++)
    acc += ws[WS_PP + ((size_t)(kc * 16 + m)) * 12288 + j];
  int sel = j >> 12, jj = j & 4095;
  int h = jj >> 7, d = jj & 127;
  ws[WS_Q + sel * 65536 + (h * 16 + m) * 128 + d] = acc;
}

// ---------------- Kernel C1: attention main pass ----------------
// lane = (m = lane&15, dq = lane>>4). Q in 32 VGPRs, O accumulated in 32 VGPRs.
// Block-level LDS reduce of the 4 waves' partials; plain coalesced partial stores.
__global__ __launch_bounds__(256, 4) void attn_kernel(const float* __restrict__ cacheK,
                                                      const float* __restrict__ cacheV,
                                                      const float* __restrict__ noise,
                                                      const float* __restrict__ taup,
                                                      float* __restrict__ ws) {
  __shared__ float red[4 * 2048];      // rotation-swizzled [wave][lane][32]
  __shared__ float sred[2][4][16];
  int h = blockIdx.x >> 5, b = blockIdx.x & 31;
  int widx = threadIdx.x >> 6, lane = threadIdx.x & 63;
  int m = lane & 15, dq = lane >> 4;
  int w64 = b * 4 + widx;  // 0..127 within head
  float inv_tau = 1.0f / taup[0];

  const float* qp = ws + WS_Q + (size_t)(h * 16 + m) * 128 + dq * 32;
  float qv[32];
  #pragma unroll
  for (int i = 0; i < 8; i++) {
    float4 t = *(const float4*)(qp + i * 4);
    qv[i * 4] = t.x; qv[i * 4 + 1] = t.y; qv[i * 4 + 2] = t.z; qv[i * 4 + 3] = t.w;
  }
  float oacc[32];
  #pragma unroll
  for (int i = 0; i < 32; i++) oacc[i] = 0.f;
  float s1 = 0.f, s2 = 0.f;

  const float* nrow = noise + (size_t)(h * 16 + m) * PM_;
  float* e2row = ws + WS_E2 + (size_t)(h * 16 + m) * PM_;
  const float* kc_base = cacheK + (size_t)h * P_ * D_;
  const float* vc_base = cacheV + (size_t)h * P_ * D_;
  const float* kn_base = ws + WS_K + (size_t)h * 16 * 128;
  const float* vn_base = ws + WS_V + (size_t)h * 16 * 128;

  for (int g = w64; g < NG_; g += 128) {
    int p0 = g * 4;
    const float *kb, *vb;
    if (p0 < P_) { kb = kc_base + (size_t)p0 * D_; vb = vc_base + (size_t)p0 * D_; }
    else { kb = kn_base + (size_t)(p0 - P_) * D_; vb = vn_base + (size_t)(p0 - P_) * D_; }

    float cc[4];
    #pragma unroll
    for (int pp = 0; pp < 4; pp++) {
      const float4* kr = (const float4*)(kb + pp * D_ + dq * 32);
      float a0 = 0.f, a1 = 0.f;
      #pragma unroll
      for (int i = 0; i < 8; i += 2) {
        float4 k4 = kr[i];
        a0 += qv[i * 4] * k4.x;     a0 += qv[i * 4 + 1] * k4.y;
        a0 += qv[i * 4 + 2] * k4.z; a0 += qv[i * 4 + 3] * k4.w;
        float4 k5 = kr[i + 1];
        a1 += qv[i * 4 + 4] * k5.x; a1 += qv[i * 4 + 5] * k5.y;
        a1 += qv[i * 4 + 6] * k5.z; a1 += qv[i * 4 + 7] * k5.w;
      }
      cc[pp] = a0 + a1;
    }
    #pragma unroll
    for (int pp = 0; pp < 4; pp++) {
      cc[pp] += __shfl_xor(cc[pp], 16, 64);
      cc[pp] += __shfl_xor(cc[pp], 32, 64);
    }
    float4 nz = *(const float4*)(nrow + p0);
    float e1v[4], e2v[4];
    e1v[0] = __expf(cc[0]); e1v[1] = __expf(cc[1]);
    e1v[2] = __expf(cc[2]); e1v[3] = __expf(cc[3]);
    e2v[0] = __expf((cc[0] + nz.x) * inv_tau);
    e2v[1] = __expf((cc[1] + nz.y) * inv_tau);
    e2v[2] = __expf((cc[2] + nz.z) * inv_tau);
    e2v[3] = __expf((cc[3] + nz.w) * inv_tau);
    s1 += e1v[0] + e1v[1] + e1v[2] + e1v[3];
    s2 += e2v[0] + e2v[1] + e2v[2] + e2v[3];
    if (dq == 0)
      *(float4*)(e2row + p0) = make_float4(e2v[0], e2v[1], e2v[2], e2v[3]);

    #pragma unroll
    for (int pp = 0; pp < 4; pp++) {
      const float4* vr = (const float4*)(vb + pp * D_ + dq * 32);
      float e = e1v[pp];
      #pragma unroll
      for (int i = 0; i < 8; i++) {
        float4 v4 = vr[i];
        oacc[i * 4] += e * v4.x;     oacc[i * 4 + 1] += e * v4.y;
        oacc[i * 4 + 2] += e * v4.z; oacc[i * 4 + 3] += e * v4.w;
      }
    }
  }

  // ---- block-level reduce (no global atomics) ----
  // rotation swizzle: phys col = (i + lane) & 31  -> 2 lanes/bank max (free)
  float* rw = red + widx * 2048 + lane * 32;
  #pragma unroll
  for (int i = 0; i < 32; i++) rw[(i + lane) & 31] = oacc[i];
  if (dq == 0) { sred[0][widx][m] = s1; sred[1][widx][m] = s2; }
  __syncthreads();

  float* po = ws + WS_PO + (size_t)(h * 32 + b) * 2048;
  for (int e = threadIdx.x; e < 2048; e += 256) {
    int ln = e >> 5, i = e & 31;
    int phys = (ln << 5) + ((i + ln) & 31);
    float v = red[phys] + red[phys + 2048] + red[phys + 4096] + red[phys + 6144];
    int mm = ln & 15, dqq = ln >> 4;
    po[mm * 128 + dqq * 32 + i] = v;
  }
  if (threadIdx.x < 16) {
    int mm = threadIdx.x;
    float a = sred[0][0][mm] + sred[0][1][mm] + sred[0][2][mm] + sred[0][3][mm];
    float c2 = sred[1][0][mm] + sred[1][1][mm] + sred[1][2][mm] + sred[1][3][mm];
    ws[WS_SP1 + (size_t)(h * 32 + b) * 16 + mm] = a;
    ws[WS_SP2 + (size_t)(h * 32 + b) * 16 + mm] = c2;
  }
}

// ---------------- Kernel S: final s1/s2 sums + 1/s2 ----------------
__global__ __launch_bounds__(256) void sums_kernel(float* __restrict__ ws) {
  int tid = blockIdx.x * 256 + threadIdx.x;
  if (tid >= 512) return;
  int h = tid >> 4, m = tid & 15;
  float a = 0.f, c2 = 0.f;
  #pragma unroll
  for (int b = 0; b < 32; b++) {
    a  += ws[WS_SP1 + (size_t)(h * 32 + b) * 16 + m];
    c2 += ws[WS_SP2 + (size_t)(h * 32 + b) * 16 + m];
  }
  ws[WS_S1 + tid] = a;
  ws[WS_S2 + tid] = c2;
  ws[WS_IS2 + tid] = 1.0f / c2;
}

// ---------------- Kernel D: o2 epilogue ----------------
__global__ __launch_bounds__(256) void epilogue_kernel(const float* __restrict__ ws,
                                                       float* __restrict__ out) {
  int tid = blockIdx.x * 256 + threadIdx.x;  // 0..65535
  int mm = tid >> 12, j = tid & 4095;
  int h = j >> 7, d = j & 127;
  float acc = 0.f;
  #pragma unroll
  for (int b = 0; b < 32; b++)
    acc += ws[WS_PO + (size_t)(h * 32 + b) * 2048 + mm * 128 + d];
  out[tid] = acc / ws[WS_S1 + h * 16 + mm];
}

// ---------------- Kernel C2: c_out ----------------
__global__ __launch_bounds__(256) void cout_kernel(const float* __restrict__ ws,
                                                   float* __restrict__ out) {
  int tid = blockIdx.x * 256 + threadIdx.x;
  if (tid >= H_ * PM_) return;
  int h = tid / PM_, p = tid % PM_;
  const float* e2b = ws + WS_E2 + (size_t)h * 16 * PM_ + p;
  const float* is2 = ws + WS_IS2 + h * 16;
  float acc = 0.f;
  #pragma unroll
  for (int mm = 0; mm < 16; mm++) acc += e2b[(size_t)mm * PM_] * is2[mm];
  out[65536 + tid] = acc;
}

extern "C" void kernel_launch(void* const* d_in, const int* in_sizes, int n_in,
                              void* d_out, int out_size, void* d_ws, size_t ws_size,
                              hipStream_t stream) {
  const float* X     = (const float*)d_in[0];
  const float* Wq    = (const float*)d_in[1];
  const float* Wk    = (const float*)d_in[2];
  const float* Wv    = (const float*)d_in[3];
  const float* cK    = (const float*)d_in[4];
  const float* cV    = (const float*)d_in[5];
  const float* tau   = (const float*)d_in[6];
  const float* noise = (const float*)d_in[7];
  float* out = (float*)d_out;
  float* ws  = (float*)d_ws;

  rmsnorm_kernel<<<16, 256, 0, stream>>>(X, ws);
  proj_kernel<<<768, 256, 0, stream>>>(Wq, Wk, Wv, ws);
  proj_reduce_kernel<<<768, 256, 0, stream>>>(ws);
  attn_kernel<<<1024, 256, 0, stream>>>(cK, cV, noise, tau, ws);
  sums_kernel<<<2, 256, 0, stream>>>(ws);
  epilogue_kernel<<<256, 256, 0, stream>>>(ws, out);
  cout_kernel<<<1026, 256, 0, stream>>>(ws, out);
}